// Round 21
// baseline (126.058 us; speedup 1.0000x reference)
//
#include <hip/hip_runtime.h>
#include <hip/hip_bf16.h>

#define SEQ   2048
#define NH    16
#define HD    64
#define BATCH 2
#define DIMM  1024

typedef __attribute__((ext_vector_type(8))) __bf16 bfrag;
typedef __attribute__((ext_vector_type(4))) float f32x4;

__device__ __forceinline__ short f2b(float f) {
  unsigned x = __float_as_uint(f);
  x += 0x7fff + ((x >> 16) & 1);
  return (short)(x >> 16);
}
__device__ __forceinline__ float b2f(short s) {
  unsigned u = ((unsigned)(unsigned short)s) << 16;
  return __uint_as_float(u);
}
// 1-op bf16 convert (RTNE) via packed cvt with both halves = f
__device__ __forceinline__ short f2b_pk(float f) {
  unsigned r;
  asm("v_cvt_pk_bf16_f32 %0, %1, %1" : "=v"(r) : "v"(f));
  return (short)r;
}

__device__ __forceinline__ void gload16(const void* g, void* l) {
  __builtin_amdgcn_global_load_lds(
      (const __attribute__((address_space(1))) void*)g,
      (__attribute__((address_space(3))) void*)l, 16, 0, 0);
}

// ---------------- fused prep: x-cvt, weight-cvt, rope table (interleaved) ----
__global__ __launch_bounds__(256) void k_prep(
    const float* __restrict__ x, const float* __restrict__ w0,
    const float* __restrict__ w1, const float* __restrict__ w2,
    const float* __restrict__ w3, short* __restrict__ xb,
    short* __restrict__ wb, float* __restrict__ cstab) {
  int b = blockIdx.x;
  if (b < 4096) {
    int i = b * 256 + threadIdx.x;
    float4 v = reinterpret_cast<const float4*>(x)[i];
    short4 o;
    o.x = f2b(v.x); o.y = f2b(v.y); o.z = f2b(v.z); o.w = f2b(v.w);
    reinterpret_cast<short4*>(xb)[i] = o;
  } else if (b < 8192) {
    int bb = b - 4096;
    int widx = bb >> 10;
    const float* src = widx == 0 ? w0 : (widx == 1 ? w1 : (widx == 2 ? w2 : w3));
    int i = (bb & 1023) * 256 + threadIdx.x;
    float4 v = reinterpret_cast<const float4*>(src)[i];
    short4 o;
    o.x = f2b(v.x); o.y = f2b(v.y); o.z = f2b(v.z); o.w = f2b(v.w);
    reinterpret_cast<short4*>(wb + (size_t)widx * 1048576)[i] = o;
  } else {
    int gid = (b - 8192) * 256 + threadIdx.x;   // 65536 total (s*32 + i)
    int s = gid >> 5, i = gid & 31;
    float freq = expf(-(float)(2 * i) * (1.0f / 64.0f) * 9.210340371976184f);
    float th = (float)s * freq;
    cstab[gid * 2]     = cosf(th);
    cstab[gid * 2 + 1] = sinf(th);
  }
}

// ---------------- QKV GEMM: [4096,1024] @ W^T ------------------------------
// BM=64 retile: grid 1536 -> 3 blocks/CU (LDS 48 KB), BK=64, XOR-swizzled
// LDS (T2), 2-phase dbuf (T3-min), XCD mapping (T1).
// Q,K stored [b,h,s,d]; V stored [b,h,d,s].
__global__ __launch_bounds__(256) void k_gemm_qkv(
    const short* __restrict__ xb, const short* __restrict__ wb,
    short* __restrict__ Qh, short* __restrict__ Kh, short* __restrict__ Vt) {
  __shared__ alignas(16) short As[2][64 * 64];
  __shared__ alignas(16) short Bs[2][128 * 64];
  const int tid = threadIdx.x;
  const int lane = tid & 63, w = tid >> 6;
  // XCD swizzle: each XCD gets 3 consecutive bn panels x all 64 bm.
  const int id = blockIdx.x;
  const int xcd = id & 7, j = id >> 3;       // j in [0,192)
  const int bn = xcd * 3 + j % 3;            // 24 bn
  const int bm = j / 3;                      // 64 bm
  const int widx = bn >> 3;            // 0=q 1=k 2=v
  const int brow0 = (bn & 7) * 128;
  const short* Wp = wb + (size_t)widx * (1 << 20);

  const int l15 = lane & 15, lq = lane >> 4, l7 = lane & 7;
  const int srow = lane >> 3;                 // 0..7
  const int sslot = l7 ^ srow;                // inverse-swizzled source slot

  f32x4 acc[4][2] = {};

  auto STAGE = [&](int buf, int kk) {
#pragma unroll
    for (int p = 0; p < 2; ++p) {
      int rr = p * 32 + w * 8 + srow;
      gload16(&xb[(size_t)(bm * 64 + rr) * 1024 + kk + sslot * 8],
              &As[buf][p * 2048 + w * 512]);
    }
#pragma unroll
    for (int p = 0; p < 4; ++p) {
      int rr = p * 32 + w * 8 + srow;
      gload16(&Wp[(size_t)(brow0 + rr) * 1024 + kk + sslot * 8],
              &Bs[buf][p * 2048 + w * 512]);
    }
  };

  STAGE(0, 0);
  __syncthreads();
  int cur = 0;
#pragma unroll 1
  for (int t = 0; t < 16; ++t) {
    if (t + 1 < 16) STAGE(cur ^ 1, (t + 1) * 64);
#pragma unroll
    for (int ks = 0; ks < 2; ++ks) {
      bfrag af[4], bf[2];
      int slot = (ks * 4 + lq) ^ l7;
#pragma unroll
      for (int mi = 0; mi < 4; ++mi)
        af[mi] = *(const bfrag*)&As[cur][(mi * 16 + l15) * 64 + slot * 8];
#pragma unroll
      for (int ni = 0; ni < 2; ++ni)
        bf[ni] = *(const bfrag*)&Bs[cur][(w * 32 + ni * 16 + l15) * 64 + slot * 8];
      __builtin_amdgcn_s_setprio(1);
#pragma unroll
      for (int mi = 0; mi < 4; ++mi)
#pragma unroll
        for (int ni = 0; ni < 2; ++ni)
          acc[mi][ni] = __builtin_amdgcn_mfma_f32_16x16x32_bf16(af[mi], bf[ni], acc[mi][ni], 0, 0, 0);
      __builtin_amdgcn_s_setprio(0);
    }
    __syncthreads();   // drains vmcnt (prefetch) + lgkmcnt (our reads)
    cur ^= 1;
  }

  if (widx < 2) {
    short* dst = widx == 0 ? Qh : Kh;
#pragma unroll
    for (int mi = 0; mi < 4; ++mi) {
#pragma unroll
      for (int ni = 0; ni < 2; ++ni) {
        int ng = bn * 128 + w * 32 + ni * 16 + l15;
        int col = ng & 1023, h = col >> 6, d = col & 63;
#pragma unroll
        for (int r = 0; r < 4; ++r) {
          int mg = bm * 64 + mi * 16 + lq * 4 + r;
          int b = mg >> 11, s = mg & 2047;
          dst[((size_t)((b * 16 + h) * 2048 + s)) * 64 + d] = f2b(acc[mi][ni][r]);
        }
      }
    }
  } else {
#pragma unroll
    for (int mi = 0; mi < 4; ++mi) {
#pragma unroll
      for (int ni = 0; ni < 2; ++ni) {
        int ng = bn * 128 + w * 32 + ni * 16 + l15;
        int col = ng & 1023, h = col >> 6, d = col & 63;
        int mg0 = bm * 64 + mi * 16 + lq * 4;
        int b = mg0 >> 11, s0 = mg0 & 2047;
        short4 sv;
        sv.x = f2b(acc[mi][ni][0]); sv.y = f2b(acc[mi][ni][1]);
        sv.z = f2b(acc[mi][ni][2]); sv.w = f2b(acc[mi][ni][3]);
        *reinterpret_cast<short4*>(
            &Vt[((size_t)((b * 16 + h) * 64 + d)) * 2048 + s0]) = sv;
      }
    }
  }
}

// ---------------- LayerNorm(64) + RoPE, vectorized 8 elems/lane -------------
// Q branch pre-scales gamma/beta by ALPHA = (1/8)*log2(e).
__global__ __launch_bounds__(256) void k_ln_rope(
    short* __restrict__ Qh, short* __restrict__ Kh,
    const float* __restrict__ qg, const float* __restrict__ qb_,
    const float* __restrict__ kg, const float* __restrict__ kb_,
    const float* __restrict__ cstab) {
  __shared__ float Ysh[32 * 64];   // 8 KB
  const int tid = threadIdx.x;
  const int rloc = tid >> 3;       // 0..31 row within block
  const int g = tid & 7;           // 8-lane group index
  const int d0 = g * 8;
  const int row = blockIdx.x * 32 + rloc;
  const int which = blockIdx.y;
  short* ptr = which ? Kh : Qh;
  const float* gamma = which ? kg : qg;
  const float* beta  = which ? kb_ : qb_;
  const float alpha = which ? 1.0f : 0.18033688011112042f;  // scale*log2e
  const int s = row & 2047;

  short vs[8];
  *reinterpret_cast<uint4*>(vs) =
      *reinterpret_cast<const uint4*>(&ptr[(size_t)row * 64 + d0]);
  float x[8];
#pragma unroll
  for (int j = 0; j < 8; ++j) x[j] = b2f(vs[j]);
  float s1 = 0.0f, s2 = 0.0f;
#pragma unroll
  for (int j = 0; j < 8; ++j) { s1 += x[j]; s2 = fmaf(x[j], x[j], s2); }
#pragma unroll
  for (int off = 1; off < 8; off <<= 1) {
    s1 += __shfl_xor(s1, off, 8);
    s2 += __shfl_xor(s2, off, 8);
  }
  float mu = s1 * (1.0f / 64.0f);
  float var = s2 * (1.0f / 64.0f) - mu * mu;
  float rs = rsqrtf(var + 1e-5f);

  float gv[8], bv[8];
  *reinterpret_cast<float4*>(&gv[0]) = *reinterpret_cast<const float4*>(&gamma[d0]);
  *reinterpret_cast<float4*>(&gv[4]) = *reinterpret_cast<const float4*>(&gamma[d0 + 4]);
  *reinterpret_cast<float4*>(&bv[0]) = *reinterpret_cast<const float4*>(&beta[d0]);
  *reinterpret_cast<float4*>(&bv[4]) = *reinterpret_cast<const float4*>(&beta[d0 + 4]);
  float y[8];
#pragma unroll
  for (int j = 0; j < 8; ++j)
    y[j] = ((x[j] - mu) * rs * gv[j] + bv[j]) * alpha;

  *reinterpret_cast<float4*>(&Ysh[rloc * 64 + d0])     = *reinterpret_cast<float4*>(&y[0]);
  *reinterpret_cast<float4*>(&Ysh[rloc * 64 + d0 + 4]) = *reinterpret_cast<float4*>(&y[4]);
  __syncthreads();

  float2 cs4[4];
  *reinterpret_cast<float4*>(&cs4[0]) =
      *reinterpret_cast<const float4*>(&cstab[((size_t)s * 32 + g * 4) * 2]);
  *reinterpret_cast<float4*>(&cs4[2]) =
      *reinterpret_cast<const float4*>(&cstab[((size_t)s * 32 + g * 4 + 2) * 2]);

  short o[8];
#pragma unroll
  for (int j = 0; j < 8; ++j) {
    int d = d0 + j;
    float pv = (d < 32) ? Ysh[rloc * 64 + 2 * d + 1]
                        : Ysh[rloc * 64 + 2 * (d - 32)];
    float c = cs4[j >> 1].x, sn = cs4[j >> 1].y;
    float ov = (d < 32) ? (y[j] * c - pv * sn) : (y[j] * c + pv * sn);
    o[j] = f2b_pk(ov);
  }
  *reinterpret_cast<uint4*>(&ptr[(size_t)row * 64 + d0]) =
      *reinterpret_cast<uint4*>(o);
}

// ---------------- causal flash attention ----------------
// 2x2 wave split (QBLK=64); V loaded DIRECTLY from global into registers
// (L2-resident — LDS staging was pure pipe overhead, guide mistake #7):
// 4 dwordx4 loads issued before STAGE_K so the compiler's counted vmcnt for
// V registers leaves the K prefetch in flight. LDS = K dbuf 16K + P 8K =
// 24576 B. Mid barrier = lgkmcnt(0) only (P visibility). One q-tile per
// block, LPT, 4 bh/XCD, diag peeled, scale pre-folded into Q (p = 2^sacc).
__global__ __launch_bounds__(256) void k_attn(
    const short* __restrict__ Qh, const short* __restrict__ Kh,
    const short* __restrict__ Vtg, short* __restrict__ Ob) {
  __shared__ alignas(16) short Ks[2][64 * 64];
  __shared__ alignas(16) short Ps[64 * 64];      // block-shared P, swizzled
  const int id = blockIdx.x;                 // 0..1023
  const int xcd = id & 7;
  const int idx = id >> 3;                   // 0..127
  const int qt = 31 - (idx >> 2);            // LPT: longest blocks first
  const int bh = xcd * 4 + (idx & 3);        // 4 bh per XCD -> L2-resident K/V
  const int b = bh >> 4, h = bh & 15;
  const int tid = threadIdx.x, lane = tid & 63, w = tid >> 6;
  const int wq = w >> 1, wk = w & 1;         // 2x2 wave split
  const short* Qp = Qh + (size_t)bh * SEQ * 64;
  const short* Kp = Kh + (size_t)bh * SEQ * 64;
  const short* Vp = Vtg + (size_t)bh * 64 * SEQ;

  const int srow = lane >> 3;                 // 0..7
  const int sslot = (lane & 7) ^ srow;        // inverse-swizzled source slot

  const int l15 = lane & 15;
  const int l7 = lane & 7;
  const int lq = lane >> 4;                   // quadrant 0..3

  auto STAGE_K = [&](int buf, int kb) {
#pragma unroll
    for (int j = 0; j < 2; ++j) {
      int rr = w * 16 + j * 8 + srow;
      gload16(&Kp[(size_t)(kb * 64 + rr) * 64 + sslot * 8],
              &Ks[buf][w * 1024 + j * 512]);
    }
  };

  const int nkb = qt + 1;

  // Q fragments: rows qt*64 + wq*32 + qt2*16 + l15, d = dc*32 + lq*8
  bfrag qf[2][2];
#pragma unroll
  for (int qt2 = 0; qt2 < 2; ++qt2)
#pragma unroll
    for (int dc = 0; dc < 2; ++dc)
      qf[qt2][dc] = *(const bfrag*)&Qp[
          (size_t)(qt * 64 + wq * 32 + qt2 * 16 + l15) * 64 + dc * 32 + lq * 8];

  // V fragment base pointers: row wk*32 + dt*16 + l15, k-offset (kc*4+lq)*8
  const short* vbase[2][2];
#pragma unroll
  for (int dt = 0; dt < 2; ++dt)
#pragma unroll
    for (int kc = 0; kc < 2; ++kc)
      vbase[dt][kc] = Vp + (size_t)(wk * 32 + dt * 16 + l15) * 2048 +
                      (kc * 4 + lq) * 8;

  f32x4 oacc[2][2] = {};
  float lrow[2][4] = {};

  union VU { uint4 u; bfrag f; };

  // one iteration body; `diag` is a compile-time-foldable flag after inlining
  auto body = [&](int kb, int cur, bool diag) {
    // V fragments for THIS tile: direct global loads (issued FIRST so the
    // counted vmcnt for their consumption leaves K prefetch in flight)
    VU vgl[2][2];
#pragma unroll
    for (int dt = 0; dt < 2; ++dt)
#pragma unroll
      for (int kc = 0; kc < 2; ++kc)
        vgl[dt][kc].u = *reinterpret_cast<const uint4*>(vbase[dt][kc] + kb * 64);

    if (!diag) STAGE_K(cur ^ 1, kb + 1);

    // ---- QK^T : wave computes S[32q][32k] at (wq,wk) ----
    f32x4 sacc[2][2] = {};
    __builtin_amdgcn_s_setprio(1);
#pragma unroll
    for (int kt = 0; kt < 2; ++kt) {
      int krow = wk * 32 + kt * 16 + l15;
#pragma unroll
      for (int dc = 0; dc < 2; ++dc) {
        bfrag kf = *(const bfrag*)&Ks[cur][krow * 64 + ((dc * 4 + lq) ^ l7) * 8];
#pragma unroll
        for (int qt2 = 0; qt2 < 2; ++qt2)
          sacc[qt2][kt] = __builtin_amdgcn_mfma_f32_16x16x32_bf16(
              qf[qt2][dc], kf, sacc[qt2][kt], 0, 0, 0);
      }
    }
    __builtin_amdgcn_s_setprio(0);

    // ---- softmax: p = 2^sacc; write P (swizzled, block-shared) ----
    const int qg0 = qt * 64 + wq * 32 + lq * 4;
#pragma unroll
    for (int qt2 = 0; qt2 < 2; ++qt2) {
#pragma unroll
      for (int kt = 0; kt < 2; ++kt) {
        int kcol = wk * 32 + kt * 16 + l15;
        int kglob = kb * 64 + kcol;
#pragma unroll
        for (int r = 0; r < 4; ++r) {
          float s2 = sacc[qt2][kt][r];
          if (diag && (kglob > qg0 + qt2 * 16 + r)) s2 = -1e30f;
          float p = __builtin_amdgcn_exp2f(s2);
          lrow[qt2][r] += p;
          int qrow = wq * 32 + qt2 * 16 + lq * 4 + r;
          int swz = (kcol >> 3) ^ (qrow & 7);
          Ps[qrow * 64 + swz * 8 + (kcol & 7)] = f2b_pk(p);
        }
      }
    }

    // ---- mid barrier: P visible (V is register-tracked; K stays in flight)
    asm volatile("s_waitcnt lgkmcnt(0)" ::: "memory");
    __builtin_amdgcn_s_barrier();
    __builtin_amdgcn_sched_barrier(0);

    // ---- PV : wave computes O[32q][32d] at (wq,wk), k = full 64 ----
    bfrag pa[2][2];
#pragma unroll
    for (int qt2 = 0; qt2 < 2; ++qt2)
#pragma unroll
      for (int kc = 0; kc < 2; ++kc)
        pa[qt2][kc] = *(const bfrag*)&Ps[
            (wq * 32 + qt2 * 16 + l15) * 64 + ((kc * 4 + lq) ^ l7) * 8];
    __builtin_amdgcn_s_setprio(1);
#pragma unroll
    for (int dt = 0; dt < 2; ++dt) {
#pragma unroll
      for (int kc = 0; kc < 2; ++kc) {
#pragma unroll
        for (int qt2 = 0; qt2 < 2; ++qt2)
          oacc[qt2][dt] = __builtin_amdgcn_mfma_f32_16x16x32_bf16(
              pa[qt2][kc], vgl[dt][kc].f, oacc[qt2][dt], 0, 0, 0);
      }
    }
    __builtin_amdgcn_s_setprio(0);
  };

  STAGE_K(0, 0);
  __syncthreads();

  int cur = 0;
#pragma unroll 1
  for (int kb = 0; kb < nkb - 1; ++kb) {
    body(kb, cur, false);
    __syncthreads();   // drains K prefetch; all PV reads of Ps done (WAR)
    cur ^= 1;
  }
  body(nkb - 1, cur, true);   // diagonal block: masked, no K prefetch

  // ---- deferred denominator: reduce over l15, then combine wk halves ----
#pragma unroll
  for (int qt2 = 0; qt2 < 2; ++qt2)
#pragma unroll
    for (int r = 0; r < 4; ++r) {
#pragma unroll
      for (int off = 1; off < 16; off <<= 1)
        lrow[qt2][r] += __shfl_xor(lrow[qt2][r], off);
    }
  __syncthreads();           // all PV reads of Ps done before aliasing
  float* Lf = (float*)Ps;    // reuse P LDS: [2 wq][2 wk][32 rows]
  if (l15 == 0) {
#pragma unroll
    for (int qt2 = 0; qt2 < 2; ++qt2)
#pragma unroll
      for (int r = 0; r < 4; ++r)
        Lf[(wq * 2 + wk) * 32 + qt2 * 16 + lq * 4 + r] = lrow[qt2][r];
  }
  __syncthreads();
  float inv[2][4];
#pragma unroll
  for (int qt2 = 0; qt2 < 2; ++qt2)
#pragma unroll
    for (int r = 0; r < 4; ++r) {
      int idx2 = qt2 * 16 + lq * 4 + r;
      inv[qt2][r] = 1.0f / (Lf[(wq * 2 + 0) * 32 + idx2] +
                            Lf[(wq * 2 + 1) * 32 + idx2]);
    }

  // ---- output: O[q][d], q = qt*64+wq*32+qt2*16+lq*4+r, d = wk*32+dt*16+l15
#pragma unroll
  for (int qt2 = 0; qt2 < 2; ++qt2) {
#pragma unroll
    for (int dt = 0; dt < 2; ++dt) {
#pragma unroll
      for (int r = 0; r < 4; ++r) {
        int qg = qt * 64 + wq * 32 + qt2 * 16 + lq * 4 + r;
        int d = wk * 32 + dt * 16 + l15;
        Ob[(size_t)(b * SEQ + qg) * 1024 + h * 64 + d] =
            f2b(oacc[qt2][dt][r] * inv[qt2][r]);
      }
    }
  }
}

// ---------------- output GEMM: Ob[4096,1024] @ Wo^T + bo -> fp32 ------------
// BM=64 tile (grid 512 -> 2 blocks/CU), BK=64, XOR swizzle, 2-phase dbuf,
// XCD mapping (bn == xcd, W panel L2-resident).
__global__ __launch_bounds__(256) void k_gemm_out(
    const short* __restrict__ Ab, const short* __restrict__ Wp,
    const float* __restrict__ bo, float* __restrict__ out) {
  __shared__ alignas(16) short As[2][64 * 64];
  __shared__ alignas(16) short Bs[2][128 * 64];
  const int tid = threadIdx.x;
  const int lane = tid & 63, w = tid >> 6;
  const int id = blockIdx.x;
  const int bn = id & 7, bm = id >> 3;   // 64 bm x 8 bn; xcd == bn
  const int brow0 = bn * 128;

  const int l15 = lane & 15, lq = lane >> 4, l7 = lane & 7;
  const int srow = lane >> 3;
  const int sslot = l7 ^ srow;

  f32x4 acc[4][2] = {};

  auto STAGE = [&](int buf, int kk) {
#pragma unroll
    for (int p = 0; p < 2; ++p) {
      int rr = p * 32 + w * 8 + srow;
      gload16(&Ab[(size_t)(bm * 64 + rr) * 1024 + kk + sslot * 8],
              &As[buf][p * 2048 + w * 512]);
    }
#pragma unroll
    for (int p = 0; p < 4; ++p) {
      int rr = p * 32 + w * 8 + srow;
      gload16(&Wp[(size_t)(brow0 + rr) * 1024 + kk + sslot * 8],
              &Bs[buf][p * 2048 + w * 512]);
    }
  };

  STAGE(0, 0);
  __syncthreads();
  int cur = 0;
#pragma unroll 1
  for (int t = 0; t < 16; ++t) {
    if (t + 1 < 16) STAGE(cur ^ 1, (t + 1) * 64);
#pragma unroll
    for (int ks = 0; ks < 2; ++ks) {
      bfrag af[4], bf[2];
      int slot = (ks * 4 + lq) ^ l7;
#pragma unroll
      for (int mi = 0; mi < 4; ++mi)
        af[mi] = *(const bfrag*)&As[cur][(mi * 16 + l15) * 64 + slot * 8];
#pragma unroll
      for (int ni = 0; ni < 2; ++ni)
        bf[ni] = *(const bfrag*)&Bs[cur][(w * 32 + ni * 16 + l15) * 64 + slot * 8];
      __builtin_amdgcn_s_setprio(1);
#pragma unroll
      for (int mi = 0; mi < 4; ++mi)
#pragma unroll
        for (int ni = 0; ni < 2; ++ni)
          acc[mi][ni] = __builtin_amdgcn_mfma_f32_16x16x32_bf16(af[mi], bf[ni], acc[mi][ni], 0, 0, 0);
      __builtin_amdgcn_s_setprio(0);
    }
    __syncthreads();
    cur ^= 1;
  }

#pragma unroll
  for (int mi = 0; mi < 4; ++mi) {
#pragma unroll
    for (int ni = 0; ni < 2; ++ni) {
      int ng = bn * 128 + w * 32 + ni * 16 + l15;
      float bias = bo[ng];
#pragma unroll
      for (int r = 0; r < 4; ++r) {
        int mg = bm * 64 + mi * 16 + lq * 4 + r;
        out[(size_t)mg * 1024 + ng] = acc[mi][ni][r] + bias;
      }
    }
  }
}

extern "C" void kernel_launch(void* const* d_in, const int* in_sizes, int n_in,
                              void* d_out, int out_size, void* d_ws, size_t ws_size,
                              hipStream_t stream) {
  const float* x  = (const float*)d_in[0];
  const float* Wq = (const float*)d_in[1];
  const float* Wk = (const float*)d_in[2];
  const float* Wv = (const float*)d_in[3];
  const float* qgamma = (const float*)d_in[4];
  const float* qbeta  = (const float*)d_in[5];
  const float* kgamma = (const float*)d_in[6];
  const float* kbeta  = (const float*)d_in[7];
  const float* Wo = (const float*)d_in[8];
  const float* bo = (const float*)d_in[9];
  float* out = (float*)d_out;

  char* ws = (char*)d_ws;
  short* xb    = (short*)(ws);
  short* wb    = (short*)(ws + 8388608);
  short* Qh    = (short*)(ws + 16777216);
  short* Kh    = (short*)(ws + 25165824);
  short* Vt    = (short*)(ws + 33554432);   // [b,h,d,s] transposed V
  short* Obuf  = (short*)(ws + 41943040);
  float* cstab = (float*)(ws + 50331648);   // interleaved (cos,sin), 512 KB

  k_prep<<<8448, 256, 0, stream>>>(x, Wq, Wk, Wv, Wo, xb, wb, cstab);

  k_gemm_qkv<<<1536, 256, 0, stream>>>(xb, wb, Qh, Kh, Vt);
  k_ln_rope<<<dim3(2048, 2), 256, 0, stream>>>(
      Qh, Kh, qgamma, qbeta, kgamma, kbeta, cstab);
  k_attn<<<1024, 256, 0, stream>>>(Qh, Kh, Vt, Obuf);
  k_gemm_out<<<512, 256, 0, stream>>>(Obuf, wb + 3145728, bo, out);
}

// Round 22
// 111.619 us; speedup vs baseline: 1.1294x; 1.1294x over previous
//
#include <hip/hip_runtime.h>
#include <hip/hip_bf16.h>

#define SEQ   2048
#define NH    16
#define HD    64
#define BATCH 2
#define DIMM  1024

typedef __attribute__((ext_vector_type(8))) __bf16 bfrag;
typedef __attribute__((ext_vector_type(4))) float f32x4;

__device__ __forceinline__ short f2b(float f) {
  unsigned x = __float_as_uint(f);
  x += 0x7fff + ((x >> 16) & 1);
  return (short)(x >> 16);
}
__device__ __forceinline__ float b2f(short s) {
  unsigned u = ((unsigned)(unsigned short)s) << 16;
  return __uint_as_float(u);
}
// 1-op bf16 convert (RTNE) via packed cvt with both halves = f
__device__ __forceinline__ short f2b_pk(float f) {
  unsigned r;
  asm("v_cvt_pk_bf16_f32 %0, %1, %1" : "=v"(r) : "v"(f));
  return (short)r;
}

__device__ __forceinline__ void gload16(const void* g, void* l) {
  __builtin_amdgcn_global_load_lds(
      (const __attribute__((address_space(1))) void*)g,
      (__attribute__((address_space(3))) void*)l, 16, 0, 0);
}

// ---------------- fused prep: x-cvt, weight-cvt, rope table (interleaved) ----
__global__ __launch_bounds__(256) void k_prep(
    const float* __restrict__ x, const float* __restrict__ w0,
    const float* __restrict__ w1, const float* __restrict__ w2,
    const float* __restrict__ w3, short* __restrict__ xb,
    short* __restrict__ wb, float* __restrict__ cstab) {
  int b = blockIdx.x;
  if (b < 4096) {
    int i = b * 256 + threadIdx.x;
    float4 v = reinterpret_cast<const float4*>(x)[i];
    short4 o;
    o.x = f2b(v.x); o.y = f2b(v.y); o.z = f2b(v.z); o.w = f2b(v.w);
    reinterpret_cast<short4*>(xb)[i] = o;
  } else if (b < 8192) {
    int bb = b - 4096;
    int widx = bb >> 10;
    const float* src = widx == 0 ? w0 : (widx == 1 ? w1 : (widx == 2 ? w2 : w3));
    int i = (bb & 1023) * 256 + threadIdx.x;
    float4 v = reinterpret_cast<const float4*>(src)[i];
    short4 o;
    o.x = f2b(v.x); o.y = f2b(v.y); o.z = f2b(v.z); o.w = f2b(v.w);
    reinterpret_cast<short4*>(wb + (size_t)widx * 1048576)[i] = o;
  } else {
    int gid = (b - 8192) * 256 + threadIdx.x;   // 65536 total (s*32 + i)
    int s = gid >> 5, i = gid & 31;
    float freq = expf(-(float)(2 * i) * (1.0f / 64.0f) * 9.210340371976184f);
    float th = (float)s * freq;
    cstab[gid * 2]     = cosf(th);
    cstab[gid * 2 + 1] = sinf(th);
  }
}

// ---------------- QKV GEMM: [4096,1024] @ W^T ------------------------------
// BM=64 retile: grid 1536 -> 3 blocks/CU (LDS 48 KB), BK=64, XOR-swizzled
// LDS (T2), 2-phase dbuf (T3-min), XCD mapping (T1).
// Q,K stored [b,h,s,d]; V stored [b,h,d,s].
__global__ __launch_bounds__(256) void k_gemm_qkv(
    const short* __restrict__ xb, const short* __restrict__ wb,
    short* __restrict__ Qh, short* __restrict__ Kh, short* __restrict__ Vt) {
  __shared__ alignas(16) short As[2][64 * 64];
  __shared__ alignas(16) short Bs[2][128 * 64];
  const int tid = threadIdx.x;
  const int lane = tid & 63, w = tid >> 6;
  // XCD swizzle: each XCD gets 3 consecutive bn panels x all 64 bm.
  const int id = blockIdx.x;
  const int xcd = id & 7, j = id >> 3;       // j in [0,192)
  const int bn = xcd * 3 + j % 3;            // 24 bn
  const int bm = j / 3;                      // 64 bm
  const int widx = bn >> 3;            // 0=q 1=k 2=v
  const int brow0 = (bn & 7) * 128;
  const short* Wp = wb + (size_t)widx * (1 << 20);

  const int l15 = lane & 15, lq = lane >> 4, l7 = lane & 7;
  const int srow = lane >> 3;                 // 0..7
  const int sslot = l7 ^ srow;                // inverse-swizzled source slot

  f32x4 acc[4][2] = {};

  auto STAGE = [&](int buf, int kk) {
#pragma unroll
    for (int p = 0; p < 2; ++p) {
      int rr = p * 32 + w * 8 + srow;
      gload16(&xb[(size_t)(bm * 64 + rr) * 1024 + kk + sslot * 8],
              &As[buf][p * 2048 + w * 512]);
    }
#pragma unroll
    for (int p = 0; p < 4; ++p) {
      int rr = p * 32 + w * 8 + srow;
      gload16(&Wp[(size_t)(brow0 + rr) * 1024 + kk + sslot * 8],
              &Bs[buf][p * 2048 + w * 512]);
    }
  };

  STAGE(0, 0);
  __syncthreads();
  int cur = 0;
#pragma unroll 1
  for (int t = 0; t < 16; ++t) {
    if (t + 1 < 16) STAGE(cur ^ 1, (t + 1) * 64);
#pragma unroll
    for (int ks = 0; ks < 2; ++ks) {
      bfrag af[4], bf[2];
      int slot = (ks * 4 + lq) ^ l7;
#pragma unroll
      for (int mi = 0; mi < 4; ++mi)
        af[mi] = *(const bfrag*)&As[cur][(mi * 16 + l15) * 64 + slot * 8];
#pragma unroll
      for (int ni = 0; ni < 2; ++ni)
        bf[ni] = *(const bfrag*)&Bs[cur][(w * 32 + ni * 16 + l15) * 64 + slot * 8];
      __builtin_amdgcn_s_setprio(1);
#pragma unroll
      for (int mi = 0; mi < 4; ++mi)
#pragma unroll
        for (int ni = 0; ni < 2; ++ni)
          acc[mi][ni] = __builtin_amdgcn_mfma_f32_16x16x32_bf16(af[mi], bf[ni], acc[mi][ni], 0, 0, 0);
      __builtin_amdgcn_s_setprio(0);
    }
    __syncthreads();   // drains vmcnt (prefetch) + lgkmcnt (our reads)
    cur ^= 1;
  }

  if (widx < 2) {
    short* dst = widx == 0 ? Qh : Kh;
#pragma unroll
    for (int mi = 0; mi < 4; ++mi) {
#pragma unroll
      for (int ni = 0; ni < 2; ++ni) {
        int ng = bn * 128 + w * 32 + ni * 16 + l15;
        int col = ng & 1023, h = col >> 6, d = col & 63;
#pragma unroll
        for (int r = 0; r < 4; ++r) {
          int mg = bm * 64 + mi * 16 + lq * 4 + r;
          int b = mg >> 11, s = mg & 2047;
          dst[((size_t)((b * 16 + h) * 2048 + s)) * 64 + d] = f2b(acc[mi][ni][r]);
        }
      }
    }
  } else {
#pragma unroll
    for (int mi = 0; mi < 4; ++mi) {
#pragma unroll
      for (int ni = 0; ni < 2; ++ni) {
        int ng = bn * 128 + w * 32 + ni * 16 + l15;
        int col = ng & 1023, h = col >> 6, d = col & 63;
        int mg0 = bm * 64 + mi * 16 + lq * 4;
        int b = mg0 >> 11, s0 = mg0 & 2047;
        short4 sv;
        sv.x = f2b(acc[mi][ni][0]); sv.y = f2b(acc[mi][ni][1]);
        sv.z = f2b(acc[mi][ni][2]); sv.w = f2b(acc[mi][ni][3]);
        *reinterpret_cast<short4*>(
            &Vt[((size_t)((b * 16 + h) * 64 + d)) * 2048 + s0]) = sv;
      }
    }
  }
}

// ---------------- LayerNorm(64) + RoPE, vectorized 8 elems/lane -------------
// Q branch pre-scales gamma/beta by ALPHA = (1/8)*log2(e).
__global__ __launch_bounds__(256) void k_ln_rope(
    short* __restrict__ Qh, short* __restrict__ Kh,
    const float* __restrict__ qg, const float* __restrict__ qb_,
    const float* __restrict__ kg, const float* __restrict__ kb_,
    const float* __restrict__ cstab) {
  __shared__ float Ysh[32 * 64];   // 8 KB
  const int tid = threadIdx.x;
  const int rloc = tid >> 3;       // 0..31 row within block
  const int g = tid & 7;           // 8-lane group index
  const int d0 = g * 8;
  const int row = blockIdx.x * 32 + rloc;
  const int which = blockIdx.y;
  short* ptr = which ? Kh : Qh;
  const float* gamma = which ? kg : qg;
  const float* beta  = which ? kb_ : qb_;
  const float alpha = which ? 1.0f : 0.18033688011112042f;  // scale*log2e
  const int s = row & 2047;

  short vs[8];
  *reinterpret_cast<uint4*>(vs) =
      *reinterpret_cast<const uint4*>(&ptr[(size_t)row * 64 + d0]);
  float x[8];
#pragma unroll
  for (int j = 0; j < 8; ++j) x[j] = b2f(vs[j]);
  float s1 = 0.0f, s2 = 0.0f;
#pragma unroll
  for (int j = 0; j < 8; ++j) { s1 += x[j]; s2 = fmaf(x[j], x[j], s2); }
#pragma unroll
  for (int off = 1; off < 8; off <<= 1) {
    s1 += __shfl_xor(s1, off, 8);
    s2 += __shfl_xor(s2, off, 8);
  }
  float mu = s1 * (1.0f / 64.0f);
  float var = s2 * (1.0f / 64.0f) - mu * mu;
  float rs = rsqrtf(var + 1e-5f);

  float gv[8], bv[8];
  *reinterpret_cast<float4*>(&gv[0]) = *reinterpret_cast<const float4*>(&gamma[d0]);
  *reinterpret_cast<float4*>(&gv[4]) = *reinterpret_cast<const float4*>(&gamma[d0 + 4]);
  *reinterpret_cast<float4*>(&bv[0]) = *reinterpret_cast<const float4*>(&beta[d0]);
  *reinterpret_cast<float4*>(&bv[4]) = *reinterpret_cast<const float4*>(&beta[d0 + 4]);
  float y[8];
#pragma unroll
  for (int j = 0; j < 8; ++j)
    y[j] = ((x[j] - mu) * rs * gv[j] + bv[j]) * alpha;

  *reinterpret_cast<float4*>(&Ysh[rloc * 64 + d0])     = *reinterpret_cast<float4*>(&y[0]);
  *reinterpret_cast<float4*>(&Ysh[rloc * 64 + d0 + 4]) = *reinterpret_cast<float4*>(&y[4]);
  __syncthreads();

  float2 cs4[4];
  *reinterpret_cast<float4*>(&cs4[0]) =
      *reinterpret_cast<const float4*>(&cstab[((size_t)s * 32 + g * 4) * 2]);
  *reinterpret_cast<float4*>(&cs4[2]) =
      *reinterpret_cast<const float4*>(&cstab[((size_t)s * 32 + g * 4 + 2) * 2]);

  short o[8];
#pragma unroll
  for (int j = 0; j < 8; ++j) {
    int d = d0 + j;
    float pv = (d < 32) ? Ysh[rloc * 64 + 2 * d + 1]
                        : Ysh[rloc * 64 + 2 * (d - 32)];
    float c = cs4[j >> 1].x, sn = cs4[j >> 1].y;
    float ov = (d < 32) ? (y[j] * c - pv * sn) : (y[j] * c + pv * sn);
    o[j] = f2b_pk(ov);
  }
  *reinterpret_cast<uint4*>(&ptr[(size_t)row * 64 + d0]) =
      *reinterpret_cast<uint4*>(o);
}

// ---------------- causal flash attention ----------------
// 2x2 wave split; single-buffered V (T4: counted-vmcnt mid-barrier keeps the
// K prefetch in flight while waiting only for V). LDS = 16K (K dbuf) + 8K (V)
// + 8K (P) = 32768 B. One q-tile per block, LPT, 4 bh/XCD, diag peeled,
// scale pre-folded into Q (p = 2^sacc).
__global__ __launch_bounds__(256) void k_attn(
    const short* __restrict__ Qh, const short* __restrict__ Kh,
    const short* __restrict__ Vtg, short* __restrict__ Ob) {
  __shared__ alignas(16) short Ks[2][64 * 64];
  __shared__ alignas(16) short Vs[64 * 64];      // single buffer
  __shared__ alignas(16) short Ps[64 * 64];      // block-shared P, swizzled
  const int id = blockIdx.x;                 // 0..1023
  const int xcd = id & 7;
  const int idx = id >> 3;                   // 0..127
  const int qt = 31 - (idx >> 2);            // LPT: longest blocks first
  const int bh = xcd * 4 + (idx & 3);        // 4 bh per XCD -> L2-resident K/V
  const int b = bh >> 4, h = bh & 15;
  const int tid = threadIdx.x, lane = tid & 63, w = tid >> 6;
  const int wq = w >> 1, wk = w & 1;         // 2x2 wave split
  const short* Qp = Qh + (size_t)bh * SEQ * 64;
  const short* Kp = Kh + (size_t)bh * SEQ * 64;
  const short* Vp = Vtg + (size_t)bh * 64 * SEQ;

  const int srow = lane >> 3;                 // 0..7
  const int sslot = (lane & 7) ^ srow;        // inverse-swizzled source slot

  const int l15 = lane & 15;
  const int l7 = lane & 7;
  const int lq = lane >> 4;                   // quadrant 0..3

  auto STAGE_K = [&](int buf, int kb) {
#pragma unroll
    for (int j = 0; j < 2; ++j) {
      int rr = w * 16 + j * 8 + srow;
      gload16(&Kp[(size_t)(kb * 64 + rr) * 64 + sslot * 8],
              &Ks[buf][w * 1024 + j * 512]);
    }
  };
  auto STAGE_V = [&](int kb) {
#pragma unroll
    for (int j = 0; j < 2; ++j) {
      int rr = w * 16 + j * 8 + srow;
      gload16(&Vp[(size_t)rr * 2048 + kb * 64 + sslot * 8],
              &Vs[w * 1024 + j * 512]);
    }
  };

  const int nkb = qt + 1;

  // Q fragments: rows qt*64 + wq*32 + qt2*16 + l15, d = dc*32 + lq*8
  bfrag qf[2][2];
#pragma unroll
  for (int qt2 = 0; qt2 < 2; ++qt2)
#pragma unroll
    for (int dc = 0; dc < 2; ++dc)
      qf[qt2][dc] = *(const bfrag*)&Qp[
          (size_t)(qt * 64 + wq * 32 + qt2 * 16 + l15) * 64 + dc * 32 + lq * 8];

  f32x4 oacc[2][2] = {};
  float lrow[2][4] = {};

  // one iteration body; `diag` is a compile-time-foldable flag after inlining
  auto body = [&](int kb, int cur, bool diag) {
    // V for THIS tile (2 loads), then K prefetch for next (2 loads)
    STAGE_V(kb);
    if (!diag) STAGE_K(cur ^ 1, kb + 1);

    // ---- QK^T : wave computes S[32q][32k] at (wq,wk) ----
    f32x4 sacc[2][2] = {};
    __builtin_amdgcn_s_setprio(1);
#pragma unroll
    for (int kt = 0; kt < 2; ++kt) {
      int krow = wk * 32 + kt * 16 + l15;
#pragma unroll
      for (int dc = 0; dc < 2; ++dc) {
        bfrag kf = *(const bfrag*)&Ks[cur][krow * 64 + ((dc * 4 + lq) ^ l7) * 8];
#pragma unroll
        for (int qt2 = 0; qt2 < 2; ++qt2)
          sacc[qt2][kt] = __builtin_amdgcn_mfma_f32_16x16x32_bf16(
              qf[qt2][dc], kf, sacc[qt2][kt], 0, 0, 0);
      }
    }
    __builtin_amdgcn_s_setprio(0);

    // ---- softmax: p = 2^sacc; write P (swizzled, block-shared) ----
    const int qg0 = qt * 64 + wq * 32 + lq * 4;
#pragma unroll
    for (int qt2 = 0; qt2 < 2; ++qt2) {
#pragma unroll
      for (int kt = 0; kt < 2; ++kt) {
        int kcol = wk * 32 + kt * 16 + l15;
        int kglob = kb * 64 + kcol;
#pragma unroll
        for (int r = 0; r < 4; ++r) {
          float s2 = sacc[qt2][kt][r];
          if (diag && (kglob > qg0 + qt2 * 16 + r)) s2 = -1e30f;
          float p = __builtin_amdgcn_exp2f(s2);
          lrow[qt2][r] += p;
          int qrow = wq * 32 + qt2 * 16 + lq * 4 + r;
          int swz = (kcol >> 3) ^ (qrow & 7);
          Ps[qrow * 64 + swz * 8 + (kcol & 7)] = f2b_pk(p);
        }
      }
    }

    // ---- mid barrier: P visible; V landed (K prefetch stays in flight) ----
    if (diag) asm volatile("s_waitcnt vmcnt(0) lgkmcnt(0)" ::: "memory");
    else      asm volatile("s_waitcnt vmcnt(2) lgkmcnt(0)" ::: "memory");
    __builtin_amdgcn_s_barrier();
    __builtin_amdgcn_sched_barrier(0);

    // ---- PV : wave computes O[32q][32d] at (wq,wk), k = full 64 ----
    bfrag pa[2][2];
#pragma unroll
    for (int qt2 = 0; qt2 < 2; ++qt2)
#pragma unroll
      for (int kc = 0; kc < 2; ++kc)
        pa[qt2][kc] = *(const bfrag*)&Ps[
            (wq * 32 + qt2 * 16 + l15) * 64 + ((kc * 4 + lq) ^ l7) * 8];
    __builtin_amdgcn_s_setprio(1);
#pragma unroll
    for (int dt = 0; dt < 2; ++dt) {
      int drow = wk * 32 + dt * 16 + l15;
#pragma unroll
      for (int kc = 0; kc < 2; ++kc) {
        bfrag vf = *(const bfrag*)&Vs[drow * 64 + ((kc * 4 + lq) ^ l7) * 8];
#pragma unroll
        for (int qt2 = 0; qt2 < 2; ++qt2)
          oacc[qt2][dt] = __builtin_amdgcn_mfma_f32_16x16x32_bf16(
              pa[qt2][kc], vf, oacc[qt2][dt], 0, 0, 0);
      }
    }
    __builtin_amdgcn_s_setprio(0);
  };

  STAGE_K(0, 0);
  __syncthreads();

  int cur = 0;
#pragma unroll 1
  for (int kb = 0; kb < nkb - 1; ++kb) {
    body(kb, cur, false);
    __syncthreads();   // drains K prefetch; all PV reads of Vs/Ps done (WAR)
    cur ^= 1;
  }
  body(nkb - 1, cur, true);   // diagonal block: masked, no K prefetch

  // ---- deferred denominator: reduce over l15, then combine wk halves ----
#pragma unroll
  for (int qt2 = 0; qt2 < 2; ++qt2)
#pragma unroll
    for (int r = 0; r < 4; ++r) {
#pragma unroll
      for (int off = 1; off < 16; off <<= 1)
        lrow[qt2][r] += __shfl_xor(lrow[qt2][r], off);
    }
  __syncthreads();           // all PV reads of Ps done before aliasing
  float* Lf = (float*)Ps;    // reuse P LDS: [2 wq][2 wk][32 rows]
  if (l15 == 0) {
#pragma unroll
    for (int qt2 = 0; qt2 < 2; ++qt2)
#pragma unroll
      for (int r = 0; r < 4; ++r)
        Lf[(wq * 2 + wk) * 32 + qt2 * 16 + lq * 4 + r] = lrow[qt2][r];
  }
  __syncthreads();
  float inv[2][4];
#pragma unroll
  for (int qt2 = 0; qt2 < 2; ++qt2)
#pragma unroll
    for (int r = 0; r < 4; ++r) {
      int idx2 = qt2 * 16 + lq * 4 + r;
      inv[qt2][r] = 1.0f / (Lf[(wq * 2 + 0) * 32 + idx2] +
                            Lf[(wq * 2 + 1) * 32 + idx2]);
    }

  // ---- output: O[q][d], q = qt*64+wq*32+qt2*16+lq*4+r, d = wk*32+dt*16+l15
#pragma unroll
  for (int qt2 = 0; qt2 < 2; ++qt2) {
#pragma unroll
    for (int dt = 0; dt < 2; ++dt) {
#pragma unroll
      for (int r = 0; r < 4; ++r) {
        int qg = qt * 64 + wq * 32 + qt2 * 16 + lq * 4 + r;
        int d = wk * 32 + dt * 16 + l15;
        Ob[(size_t)(b * SEQ + qg) * 1024 + h * 64 + d] =
            f2b(oacc[qt2][dt][r] * inv[qt2][r]);
      }
    }
  }
}

// ---------------- output GEMM: Ob[4096,1024] @ Wo^T + bo -> fp32 ------------
// BM=64 tile (grid 512 -> 2 blocks/CU), BK=64, XOR swizzle, 2-phase dbuf,
// XCD mapping (bn == xcd, W panel L2-resident).
__global__ __launch_bounds__(256) void k_gemm_out(
    const short* __restrict__ Ab, const short* __restrict__ Wp,
    const float* __restrict__ bo, float* __restrict__ out) {
  __shared__ alignas(16) short As[2][64 * 64];
  __shared__ alignas(16) short Bs[2][128 * 64];
  const int tid = threadIdx.x;
  const int lane = tid & 63, w = tid >> 6;
  const int id = blockIdx.x;
  const int bn = id & 7, bm = id >> 3;   // 64 bm x 8 bn; xcd == bn
  const int brow0 = bn * 128;

  const int l15 = lane & 15, lq = lane >> 4, l7 = lane & 7;
  const int srow = lane >> 3;
  const int sslot = l7 ^ srow;

  f32x4 acc[4][2] = {};

  auto STAGE = [&](int buf, int kk) {
#pragma unroll
    for (int p = 0; p < 2; ++p) {
      int rr = p * 32 + w * 8 + srow;
      gload16(&Ab[(size_t)(bm * 64 + rr) * 1024 + kk + sslot * 8],
              &As[buf][p * 2048 + w * 512]);
    }
#pragma unroll
    for (int p = 0; p < 4; ++p) {
      int rr = p * 32 + w * 8 + srow;
      gload16(&Wp[(size_t)(brow0 + rr) * 1024 + kk + sslot * 8],
              &Bs[buf][p * 2048 + w * 512]);
    }
  };

  STAGE(0, 0);
  __syncthreads();
  int cur = 0;
#pragma unroll 1
  for (int t = 0; t < 16; ++t) {
    if (t + 1 < 16) STAGE(cur ^ 1, (t + 1) * 64);
#pragma unroll
    for (int ks = 0; ks < 2; ++ks) {
      bfrag af[4], bf[2];
      int slot = (ks * 4 + lq) ^ l7;
#pragma unroll
      for (int mi = 0; mi < 4; ++mi)
        af[mi] = *(const bfrag*)&As[cur][(mi * 16 + l15) * 64 + slot * 8];
#pragma unroll
      for (int ni = 0; ni < 2; ++ni)
        bf[ni] = *(const bfrag*)&Bs[cur][(w * 32 + ni * 16 + l15) * 64 + slot * 8];
      __builtin_amdgcn_s_setprio(1);
#pragma unroll
      for (int mi = 0; mi < 4; ++mi)
#pragma unroll
        for (int ni = 0; ni < 2; ++ni)
          acc[mi][ni] = __builtin_amdgcn_mfma_f32_16x16x32_bf16(af[mi], bf[ni], acc[mi][ni], 0, 0, 0);
      __builtin_amdgcn_s_setprio(0);
    }
    __syncthreads();
    cur ^= 1;
  }

#pragma unroll
  for (int mi = 0; mi < 4; ++mi) {
#pragma unroll
    for (int ni = 0; ni < 2; ++ni) {
      int ng = bn * 128 + w * 32 + ni * 16 + l15;
      float bias = bo[ng];
#pragma unroll
      for (int r = 0; r < 4; ++r) {
        int mg = bm * 64 + mi * 16 + lq * 4 + r;
        out[(size_t)mg * 1024 + ng] = acc[mi][ni][r] + bias;
      }
    }
  }
}

extern "C" void kernel_launch(void* const* d_in, const int* in_sizes, int n_in,
                              void* d_out, int out_size, void* d_ws, size_t ws_size,
                              hipStream_t stream) {
  const float* x  = (const float*)d_in[0];
  const float* Wq = (const float*)d_in[1];
  const float* Wk = (const float*)d_in[2];
  const float* Wv = (const float*)d_in[3];
  const float* qgamma = (const float*)d_in[4];
  const float* qbeta  = (const float*)d_in[5];
  const float* kgamma = (const float*)d_in[6];
  const float* kbeta  = (const float*)d_in[7];
  const float* Wo = (const float*)d_in[8];
  const float* bo = (const float*)d_in[9];
  float* out = (float*)d_out;

  char* ws = (char*)d_ws;
  short* xb    = (short*)(ws);
  short* wb    = (short*)(ws + 8388608);
  short* Qh    = (short*)(ws + 16777216);
  short* Kh    = (short*)(ws + 25165824);
  short* Vt    = (short*)(ws + 33554432);   // [b,h,d,s] transposed V
  short* Obuf  = (short*)(ws + 41943040);
  float* cstab = (float*)(ws + 50331648);   // interleaved (cos,sin), 512 KB

  k_prep<<<8448, 256, 0, stream>>>(x, Wq, Wk, Wv, Wo, xb, wb, cstab);

  k_gemm_qkv<<<1536, 256, 0, stream>>>(xb, wb, Qh, Kh, Vt);
  k_ln_rope<<<dim3(2048, 2), 256, 0, stream>>>(
      Qh, Kh, qgamma, qbeta, kgamma, kbeta, cstab);
  k_attn<<<1024, 256, 0, stream>>>(Qh, Kh, Vt, Obuf);
  k_gemm_out<<<512, 256, 0, stream>>>(Obuf, wb + 3145728, bo, out);
}